// Round 18
// baseline (102.190 us; speedup 1.0000x reference)
//
#include <hip/hip_runtime.h>
#include <math.h>

#define NB 4096

#define SCALE_POS 2.0f
#define SCALE_NEG 50.0f
#define THRESH    0.7f
#define MARGIN    0.1f
#define GAMMA     0.3f
#define EPS_SELF  1e-5f

typedef __attribute__((ext_vector_type(8))) short s16x8;
typedef __attribute__((ext_vector_type(16))) float f32x16;
typedef unsigned long long u64;
typedef unsigned int u32;
typedef unsigned char u8;

__device__ __forceinline__ short f2bf(float x) {  // RNE to bf16
  u32 u = __float_as_uint(x);
  return (short)((u + 0x7FFFu + ((u >> 16) & 1u)) >> 16);
}
__device__ __forceinline__ float bf2f(short h) {
  return __uint_as_float(((u32)(unsigned short)h) << 16);
}
// Monotone 16-bit key for bf16 bit patterns (order-preserving)
__device__ __forceinline__ u32 mono16(u32 h) {
  return (h & 0x8000u) ? (h ^ 0xFFFFu) : (h | 0x8000u);
}
__device__ __forceinline__ float unmono16(u32 m) {
  u32 h = (m & 0x8000u) ? (m & 0x7FFFu) : (~m & 0xFFFFu);
  return bf2f((short)h);
}
// Row permutation: physical fragment slot p holds logical row Lmap(p).
__device__ __forceinline__ int Lmap(int p) {
  return (p & ~63) + 2 * (p & 31) + ((p >> 5) & 1);
}
__device__ __forceinline__ int Linv(int c) {
  return (c & ~63) + ((c & 1) << 5) + ((c >> 1) & 31);
}

// ---------------------------------------------------------------------------
// K1: fp32 -> split-bf16 fragment-major F (32x32x16 MFMA), rows permuted by
// Lmap within each 64-row group. Labels packed to u8; zero buckets + ticket.
__global__ __launch_bounds__(256) void k1_convert(
    const float* __restrict__ emb, const int* __restrict__ labels,
    short* __restrict__ F, u8* __restrict__ labu8,
    float* __restrict__ buckets, u32* __restrict__ ticket) {
  int t = blockIdx.x * 256 + threadIdx.x;  // 0..65535
  int T = t >> 9, s = (t >> 6) & 7, l = t & 63;
  int lrow = Lmap(T * 32 + (l & 31));  // logical source row for this slot
  int c4 = s * 4 + (l >> 5) * 2;
  const float4* e4 = (const float4*)emb;
  float4 v0 = e4[lrow * 32 + c4];
  float4 v1 = e4[lrow * 32 + c4 + 1];
  float xs[8] = {v0.x, v0.y, v0.z, v0.w, v1.x, v1.y, v1.z, v1.w};
  s16x8 h, lo;
#pragma unroll
  for (int e = 0; e < 8; ++e) {
    short hh = f2bf(xs[e]);
    h[e] = hh;
    lo[e] = f2bf(xs[e] - bf2f(hh));
  }
  ((s16x8*)F)[(T * 16 + s) * 64 + l] = h;
  ((s16x8*)F)[(T * 16 + 8 + s) * 64 + l] = lo;
  if (t < 1024) {
    int4 lb = ((const int4*)labels)[t];
    uchar4 p;
    p.x = (u8)lb.x; p.y = (u8)lb.y; p.z = (u8)lb.z; p.w = (u8)lb.w;
    ((uchar4*)labu8)[t] = p;
  }
  if (t < 32) buckets[t] = 0.0f;
  if (t == 32) ticket[0] = 0u;
}

// ---------------------------------------------------------------------------
// K2: Gram GEMM (32x32x16 split-bf16, 2-TERM: HH + H.L^T) -> bf16 sim,
// packed full-line u32 stores. blockIdx.x = ROW tile group -> each 128-row
// band of sim is written from one XCD (L2-resident for pinned readers).
__global__ __launch_bounds__(256, 4) void k2_pass1(
    const short* __restrict__ F, short* __restrict__ simh) {
  int tid = threadIdx.x, w = tid >> 6, l = tid & 63;
  int lo5 = l & 31, hi = l >> 5;
  int mt0 = blockIdx.x * 4 + (w >> 1) * 2;  // 32-row tile idx (x = rows!)
  int nt0 = blockIdx.y * 4 + (w & 1) * 2;   // 32-col tile idx (even)
  const s16x8* F8 = (const s16x8*)F;

  f32x16 acc[2][2] = {};
#pragma unroll 1
  for (int s = 0; s < 8; ++s) {
    s16x8 ah[2], bh[2], bl[2];
#pragma unroll
    for (int t = 0; t < 2; ++t) {
      int ia = ((mt0 + t) * 16 + s) * 64 + l;
      int ib = ((nt0 + t) * 16 + s) * 64 + l;
      ah[t] = F8[ia];                        // A hi only (LH term dropped)
      bh[t] = F8[ib]; bl[t] = F8[ib + 512];  // B hi + lo
    }
#pragma unroll
    for (int ti = 0; ti < 2; ++ti)
#pragma unroll
      for (int tj = 0; tj < 2; ++tj) {
        acc[ti][tj] = __builtin_amdgcn_mfma_f32_32x32x16_bf16(ah[ti], bh[tj], acc[ti][tj], 0, 0, 0);
        acc[ti][tj] = __builtin_amdgcn_mfma_f32_32x32x16_bf16(ah[ti], bl[tj], acc[ti][tj], 0, 0, 0);
      }
  }

  u32* sim32 = (u32*)simh;
  int cg = nt0 >> 1;  // 64-col group
#pragma unroll
  for (int ti = 0; ti < 2; ++ti)
#pragma unroll
    for (int q = 0; q < 4; ++q)
#pragma unroll
      for (int rr = 0; rr < 4; ++rr) {
        int reg = q * 4 + rr;
        int m = (mt0 + ti) * 32 + q * 8 + hi * 4 + rr;  // physical row
        u32 pv = ((u32)(unsigned short)f2bf(acc[ti][1][reg]) << 16) |
                 (u32)(unsigned short)f2bf(acc[ti][0][reg]);
        sim32[(size_t)m * (NB / 2) + cg * 32 + lo5] = pv;
      }
}

// ---------------------------------------------------------------------------
// K4: wave-pair per row fused mine + loss (R15 form), XCD-pinned, with the
// final mean folded in: one atomicAdd per block into 32 buckets, last block
// (ticket) sums buckets and writes out[0]. No separate k5 launch.
__global__ __launch_bounds__(256) void k4_row(
    const short* __restrict__ simh, const u8* __restrict__ labu8,
    float* __restrict__ buckets, u32* __restrict__ ticket,
    float* __restrict__ out) {
  int w = threadIdx.x >> 6, l = threadIdx.x & 63;
  int r = w >> 1;              // row slot in block
  int h = w & 1;               // column half
  int v = blockIdx.x;          // 0..2047
  int xcd = v & 7, slot = v >> 3;          // slot 0..255
  int rb = xcd + 8 * (slot >> 6);          // 128-row band, rb%8==xcd
  int inner = slot & 63;                   // 64 blocks per band
  int i = rb * 128 + inner * 2 + r;        // physical row
  int L = Lmap(i);
  int lm = (int)labu8[L];
  const s16x8* sI = (const s16x8*)(simh + (size_t)i * NB);
  const u64* L8 = (const u64*)labu8;
  int cbase = h * 256;  // chunk base of this half

  s16x8 a[4];
  u64 lab[4];
#pragma unroll
  for (int ch = 0; ch < 4; ++ch) a[ch] = sI[cbase + ch * 64 + l];
#pragma unroll
  for (int ch = 0; ch < 4; ++ch) lab[ch] = L8[cbase + ch * 64 + l];

  u32 pk = 0xFFFFFFFFu;  // min over (mono16(bf16)<<16 | n)
  u32 nk = 0u;           // max over same packing
  u32 posm = 0u;         // bit ch*8+e: label match
#pragma unroll
  for (int ch = 0; ch < 4; ++ch) {
    int nb = (cbase + ch * 64 + l) * 8;
#pragma unroll
    for (int e = 0; e < 8; ++e) {
      u32 hb = (u32)(unsigned short)a[ch][e];
      u32 key = (mono16(hb) << 16) | (u32)(nb + e);
      int ln = (int)((lab[ch] >> (8 * e)) & 255u);
      if (ln == lm) {
        posm |= (1u << (ch * 8 + e));
        float s = bf2f((short)hb);
        if (s < 1.0f - EPS_SELF) pk = pk < key ? pk : key;
      } else {
        nk = nk > key ? nk : key;
      }
    }
  }
#pragma unroll
  for (int d = 1; d < 64; d <<= 1) {
    u32 po = __shfl_xor(pk, d, 64); pk = pk < po ? pk : po;
    u32 no = __shfl_xor(nk, d, 64); nk = nk > no ? nk : no;
  }
  __shared__ u32 spk[4], snk[4];
  if (l == 0) { spk[w] = pk; snk[w] = nk; }
  __syncthreads();
  u32 P0 = spk[r * 2], P1 = spk[r * 2 + 1];
  u32 N0 = snk[r * 2], N1 = snk[r * 2 + 1];
  u32 Pk = P0 < P1 ? P0 : P1;
  u32 Nk = N0 > N1 ? N0 : N1;
  float minpos = unmono16(Pk >> 16);  // NaN if no positive
  float maxneg = unmono16(Nk >> 16);  // NaN if no negative
  bool valid = (maxneg + MARGIN > minpos);
  int jp = valid ? Linv((int)(Pk & 0xFFFFu)) : i;  // physical row of j
  float mp = minpos, mx = maxneg;
  float dpp = minpos - 1.0f;  // e_i.d_p = sim_ij - 1 (unit rows)
  float inpp = rsqrtf(fmaxf(2.0f - 2.0f * minpos, 1e-12f));
  float cg = GAMMA * inpp;    // row-uniform

  const s16x8* sJ = (const s16x8*)(simh + (size_t)jp * NB);
  s16x8 b[4];
#pragma unroll
  for (int ch = 0; ch < 4; ++ch) b[ch] = sJ[cbase + ch * 64 + l];

  float ps = 0.0f, ns = 0.0f;
#pragma unroll
  for (int ch = 0; ch < 4; ++ch) {
#pragma unroll
    for (int e = 0; e < 8; ++e) {
      float s = bf2f(a[ch][e]);
      if ((posm >> (ch * 8 + e)) & 1u) {
        if (s < 1.0f - EPS_SELF && s - MARGIN < mx)
          ps += __expf(-SCALE_POS * (s - THRESH));
      } else if (s + MARGIN > mp) {
        float sjv = bf2f(b[ch][e]);
        float inn = rsqrtf(fmaxf(2.0f - 2.0f * s, 1e-12f));
        float rg = cg * (sjv - s - dpp) * inn;
        ns += __expf(SCALE_NEG * (s - THRESH - rg));
      }
    }
  }
#pragma unroll
  for (int d = 1; d < 64; d <<= 1) {
    ps += __shfl_xor(ps, d, 64);
    ns += __shfl_xor(ns, d, 64);
  }
  __shared__ float redp[4], redn[4];
  __shared__ int sval[2];
  if (l == 0) {
    redp[w] = ps;
    redn[w] = ns;
    if (h == 0) sval[r] = valid ? 1 : 0;
  }
  __syncthreads();
  if (threadIdx.x == 0) {
    float t0 = sval[0] ? (log1pf(redp[0] + redp[1]) * (1.0f / SCALE_POS) +
                          log1pf(redn[0] + redn[1]) * (1.0f / SCALE_NEG))
                       : 0.0f;
    float t1 = sval[1] ? (log1pf(redp[2] + redp[3]) * (1.0f / SCALE_POS) +
                          log1pf(redn[2] + redn[3]) * (1.0f / SCALE_NEG))
                       : 0.0f;
    atomicAdd(&buckets[blockIdx.x & 31], t0 + t1);
    __threadfence();
    u32 old = atomicAdd(ticket, 1u);
    if (old == 2047u) {  // last block: fold buckets (atomic-read is coherent)
      float tot = 0.0f;
#pragma unroll
      for (int q = 0; q < 32; ++q) tot += atomicAdd(&buckets[q], 0.0f);
      out[0] = tot * (1.0f / (float)NB);
    }
  }
}

// ---------------------------------------------------------------------------
extern "C" void kernel_launch(void* const* d_in, const int* in_sizes, int n_in,
                              void* d_out, int out_size, void* d_ws, size_t ws_size,
                              hipStream_t stream) {
  const float* emb = (const float*)d_in[0];
  const int* labels = (const int*)d_in[1];
  float* out = (float*)d_out;
  char* ws = (char*)d_ws;

  short* simh = (short*)ws;                               // 32 MB bf16 sim
  short* F = (short*)(ws + ((size_t)NB * NB * 2));        // 2 MB split-bf16 frags
  char* base = ws + ((size_t)NB * NB * 2) + (2 << 20);
  u8* labu8 = (u8*)(base);                                // 4 KB
  float* buckets = (float*)(base + 4096);                 // 128 B
  u32* ticket = (u32*)(base + 8192);                      // 4 B

  hipLaunchKernelGGL(k1_convert, dim3(256), dim3(256), 0, stream,
                     emb, labels, F, labu8, buckets, ticket);
  hipLaunchKernelGGL(k2_pass1, dim3(NB / 128, NB / 128), dim3(256), 0, stream,
                     F, simh);
  hipLaunchKernelGGL(k4_row, dim3(NB / 2), dim3(256), 0, stream,
                     simh, labu8, buckets, ticket, out);
}

// Round 19
// 47.544 us; speedup vs baseline: 2.1494x; 2.1494x over previous
//
#include <hip/hip_runtime.h>
#include <math.h>

#define NB 4096

#define SCALE_POS 2.0f
#define SCALE_NEG 50.0f
#define THRESH    0.7f
#define MARGIN    0.1f
#define GAMMA     0.3f
#define EPS_SELF  1e-5f

typedef __attribute__((ext_vector_type(8))) short s16x8;
typedef __attribute__((ext_vector_type(16))) float f32x16;
typedef unsigned long long u64;
typedef unsigned int u32;
typedef unsigned char u8;

__device__ __forceinline__ short f2bf(float x) {  // RNE to bf16
  u32 u = __float_as_uint(x);
  return (short)((u + 0x7FFFu + ((u >> 16) & 1u)) >> 16);
}
__device__ __forceinline__ float bf2f(short h) {
  return __uint_as_float(((u32)(unsigned short)h) << 16);
}
// Monotone 16-bit key for bf16 bit patterns (order-preserving)
__device__ __forceinline__ u32 mono16(u32 h) {
  return (h & 0x8000u) ? (h ^ 0xFFFFu) : (h | 0x8000u);
}
__device__ __forceinline__ float unmono16(u32 m) {
  u32 h = (m & 0x8000u) ? (m & 0x7FFFu) : (~m & 0xFFFFu);
  return bf2f((short)h);
}
// Row permutation: physical fragment slot p holds logical row Lmap(p).
// Lmap(64g + 32r + q) = 64g + 2q + r  (q=0..31, r=0..1)
__device__ __forceinline__ int Lmap(int p) {
  return (p & ~63) + 2 * (p & 31) + ((p >> 5) & 1);
}
// Inverse: Linv(64g + 2q + r) = 64g + 32r + q
__device__ __forceinline__ int Linv(int c) {
  return (c & ~63) + ((c & 1) << 5) + ((c >> 1) & 31);
}

// ---------------------------------------------------------------------------
// K1: fp32 -> split-bf16 fragment-major F (32x32x16 MFMA), rows permuted by
// Lmap within each 64-row group. Labels packed to u8 in NATURAL order.
__global__ __launch_bounds__(256) void k1_convert(
    const float* __restrict__ emb, const int* __restrict__ labels,
    short* __restrict__ F, u8* __restrict__ labu8) {
  int t = blockIdx.x * 256 + threadIdx.x;  // 0..65535
  int T = t >> 9, s = (t >> 6) & 7, l = t & 63;
  int lrow = Lmap(T * 32 + (l & 31));  // logical source row for this slot
  int c4 = s * 4 + (l >> 5) * 2;
  const float4* e4 = (const float4*)emb;
  float4 v0 = e4[lrow * 32 + c4];
  float4 v1 = e4[lrow * 32 + c4 + 1];
  float xs[8] = {v0.x, v0.y, v0.z, v0.w, v1.x, v1.y, v1.z, v1.w};
  s16x8 h, lo;
#pragma unroll
  for (int e = 0; e < 8; ++e) {
    short hh = f2bf(xs[e]);
    h[e] = hh;
    lo[e] = f2bf(xs[e] - bf2f(hh));
  }
  ((s16x8*)F)[(T * 16 + s) * 64 + l] = h;
  ((s16x8*)F)[(T * 16 + 8 + s) * 64 + l] = lo;
  if (t < 1024) {
    int4 lb = ((const int4*)labels)[t];
    uchar4 p;
    p.x = (u8)lb.x; p.y = (u8)lb.y; p.z = (u8)lb.z; p.w = (u8)lb.w;
    ((uchar4*)labu8)[t] = p;
  }
}

// ---------------------------------------------------------------------------
// K2: Gram GEMM (32x32x16 split-bf16, 2-TERM: HH + H.L^T) -> bf16 sim,
// packed full-line u32 stores. blockIdx.x = ROW tile group -> each 128-row
// band of sim is written from one XCD (L2-resident for k4's pinned readers).
__global__ __launch_bounds__(256, 4) void k2_pass1(
    const short* __restrict__ F, short* __restrict__ simh) {
  int tid = threadIdx.x, w = tid >> 6, l = tid & 63;
  int lo5 = l & 31, hi = l >> 5;
  int mt0 = blockIdx.x * 4 + (w >> 1) * 2;  // 32-row tile idx (x = rows!)
  int nt0 = blockIdx.y * 4 + (w & 1) * 2;   // 32-col tile idx (even)
  const s16x8* F8 = (const s16x8*)F;

  f32x16 acc[2][2] = {};
#pragma unroll 1
  for (int s = 0; s < 8; ++s) {
    s16x8 ah[2], bh[2], bl[2];
#pragma unroll
    for (int t = 0; t < 2; ++t) {
      int ia = ((mt0 + t) * 16 + s) * 64 + l;
      int ib = ((nt0 + t) * 16 + s) * 64 + l;
      ah[t] = F8[ia];                        // A hi only (LH term dropped)
      bh[t] = F8[ib]; bl[t] = F8[ib + 512];  // B hi + lo
    }
#pragma unroll
    for (int ti = 0; ti < 2; ++ti)
#pragma unroll
      for (int tj = 0; tj < 2; ++tj) {
        acc[ti][tj] = __builtin_amdgcn_mfma_f32_32x32x16_bf16(ah[ti], bh[tj], acc[ti][tj], 0, 0, 0);
        acc[ti][tj] = __builtin_amdgcn_mfma_f32_32x32x16_bf16(ah[ti], bl[tj], acc[ti][tj], 0, 0, 0);
      }
  }

  u32* sim32 = (u32*)simh;
  int cg = nt0 >> 1;  // 64-col group
#pragma unroll
  for (int ti = 0; ti < 2; ++ti)
#pragma unroll
    for (int q = 0; q < 4; ++q)
#pragma unroll
      for (int rr = 0; rr < 4; ++rr) {
        int reg = q * 4 + rr;
        int m = (mt0 + ti) * 32 + q * 8 + hi * 4 + rr;  // physical row
        u32 pv = ((u32)(unsigned short)f2bf(acc[ti][1][reg]) << 16) |
                 (u32)(unsigned short)f2bf(acc[ti][0][reg]);
        sim32[(size_t)m * (NB / 2) + cg * 32 + lo5] = pv;
      }
}

// ---------------------------------------------------------------------------
// K4: wave-pair per row fused mine + loss, XCD-pinned (the block reading
// 128-row band rb runs on XCD rb%8, whose L2 holds that band). Divergent
// loss loop (R15 form — beats branchless on this data).
__global__ __launch_bounds__(256) void k4_row(
    const short* __restrict__ simh, const u8* __restrict__ labu8,
    float* __restrict__ rowloss) {
  int w = threadIdx.x >> 6, l = threadIdx.x & 63;
  int r = w >> 1;              // row slot in block
  int h = w & 1;               // column half
  int v = blockIdx.x;          // 0..2047
  int xcd = v & 7, slot = v >> 3;          // slot 0..255
  int rb = xcd + 8 * (slot >> 6);          // 128-row band, rb%8==xcd
  int inner = slot & 63;                   // 64 blocks per band
  int i = rb * 128 + inner * 2 + r;        // physical row
  int L = Lmap(i);
  int lm = (int)labu8[L];
  const s16x8* sI = (const s16x8*)(simh + (size_t)i * NB);
  const u64* L8 = (const u64*)labu8;
  int cbase = h * 256;  // chunk base of this half

  s16x8 a[4];
  u64 lab[4];
#pragma unroll
  for (int ch = 0; ch < 4; ++ch) a[ch] = sI[cbase + ch * 64 + l];
#pragma unroll
  for (int ch = 0; ch < 4; ++ch) lab[ch] = L8[cbase + ch * 64 + l];

  u32 pk = 0xFFFFFFFFu;  // min over (mono16(bf16)<<16 | n)
  u32 nk = 0u;           // max over same packing
  u32 posm = 0u;         // bit ch*8+e: label match
#pragma unroll
  for (int ch = 0; ch < 4; ++ch) {
    int nb = (cbase + ch * 64 + l) * 8;
#pragma unroll
    for (int e = 0; e < 8; ++e) {
      u32 hb = (u32)(unsigned short)a[ch][e];
      u32 key = (mono16(hb) << 16) | (u32)(nb + e);
      int ln = (int)((lab[ch] >> (8 * e)) & 255u);
      if (ln == lm) {
        posm |= (1u << (ch * 8 + e));
        float s = bf2f((short)hb);
        if (s < 1.0f - EPS_SELF) pk = pk < key ? pk : key;
      } else {
        nk = nk > key ? nk : key;
      }
    }
  }
#pragma unroll
  for (int d = 1; d < 64; d <<= 1) {
    u32 po = __shfl_xor(pk, d, 64); pk = pk < po ? pk : po;
    u32 no = __shfl_xor(nk, d, 64); nk = nk > no ? nk : no;
  }
  __shared__ u32 spk[4], snk[4];
  if (l == 0) { spk[w] = pk; snk[w] = nk; }
  __syncthreads();
  u32 P0 = spk[r * 2], P1 = spk[r * 2 + 1];
  u32 N0 = snk[r * 2], N1 = snk[r * 2 + 1];
  u32 Pk = P0 < P1 ? P0 : P1;
  u32 Nk = N0 > N1 ? N0 : N1;
  float minpos = unmono16(Pk >> 16);  // NaN if no positive
  float maxneg = unmono16(Nk >> 16);  // NaN if no negative
  bool valid = (maxneg + MARGIN > minpos);
  int jp = valid ? Linv((int)(Pk & 0xFFFFu)) : i;  // physical row of j
  float mp = minpos, mx = maxneg;
  float dpp = minpos - 1.0f;  // e_i.d_p = sim_ij - 1 (unit rows)
  float inpp = rsqrtf(fmaxf(2.0f - 2.0f * minpos, 1e-12f));
  float cg = GAMMA * inpp;    // row-uniform hoist

  const s16x8* sJ = (const s16x8*)(simh + (size_t)jp * NB);
  s16x8 b[4];
#pragma unroll
  for (int ch = 0; ch < 4; ++ch) b[ch] = sJ[cbase + ch * 64 + l];

  float ps = 0.0f, ns = 0.0f;
#pragma unroll
  for (int ch = 0; ch < 4; ++ch) {
#pragma unroll
    for (int e = 0; e < 8; ++e) {
      float s = bf2f(a[ch][e]);
      if ((posm >> (ch * 8 + e)) & 1u) {
        if (s < 1.0f - EPS_SELF && s - MARGIN < mx)
          ps += __expf(-SCALE_POS * (s - THRESH));
      } else if (s + MARGIN > mp) {
        float sjv = bf2f(b[ch][e]);
        float inn = rsqrtf(fmaxf(2.0f - 2.0f * s, 1e-12f));
        float rg = cg * (sjv - s - dpp) * inn;
        ns += __expf(SCALE_NEG * (s - THRESH - rg));
      }
    }
  }
#pragma unroll
  for (int d = 1; d < 64; d <<= 1) {
    ps += __shfl_xor(ps, d, 64);
    ns += __shfl_xor(ns, d, 64);
  }
  __shared__ float redp[4], redn[4];
  if (l == 0) { redp[w] = ps; redn[w] = ns; }
  __syncthreads();
  if (l == 0 && h == 0) {
    float tp = redp[r * 2] + redp[r * 2 + 1];
    float tn = redn[r * 2] + redn[r * 2 + 1];
    rowloss[i] = valid ? (log1pf(tp) * (1.0f / SCALE_POS) + log1pf(tn) * (1.0f / SCALE_NEG))
                       : 0.0f;
  }
}

// ---------------------------------------------------------------------------
// K5: mean over rows. Single block.
__global__ __launch_bounds__(1024) void k5_final(
    const float* __restrict__ rowloss, float* __restrict__ out) {
  int tid = threadIdx.x;
  float local = 0.0f;
  for (int r = tid; r < NB; r += 1024) local += rowloss[r];
#pragma unroll
  for (int d = 1; d < 64; d <<= 1) local += __shfl_xor(local, d, 64);
  __shared__ float partial[16];
  if ((tid & 63) == 0) partial[tid >> 6] = local;
  __syncthreads();
  if (tid == 0) {
    float t = 0.0f;
#pragma unroll
    for (int q = 0; q < 16; ++q) t += partial[q];
    out[0] = t / (float)NB;
  }
}

// ---------------------------------------------------------------------------
extern "C" void kernel_launch(void* const* d_in, const int* in_sizes, int n_in,
                              void* d_out, int out_size, void* d_ws, size_t ws_size,
                              hipStream_t stream) {
  const float* emb = (const float*)d_in[0];
  const int* labels = (const int*)d_in[1];
  float* out = (float*)d_out;
  char* ws = (char*)d_ws;

  short* simh = (short*)ws;                               // 32 MB bf16 sim
  short* F = (short*)(ws + ((size_t)NB * NB * 2));        // 2 MB split-bf16 frags
  char* base = ws + ((size_t)NB * NB * 2) + (2 << 20);
  float* rowloss = (float*)(base);                        // 16 KB
  u8* labu8 = (u8*)(base + 16384);                        // 4 KB

  hipLaunchKernelGGL(k1_convert, dim3(256), dim3(256), 0, stream,
                     emb, labels, F, labu8);
  hipLaunchKernelGGL(k2_pass1, dim3(NB / 128, NB / 128), dim3(256), 0, stream,
                     F, simh);
  hipLaunchKernelGGL(k4_row, dim3(NB / 2), dim3(256), 0, stream,
                     simh, labu8, rowloss);
  hipLaunchKernelGGL(k5_final, dim3(1), dim3(1024), 0, stream, rowloss, out);
}